// Round 11
// baseline (447.442 us; speedup 1.0000x reference)
//
#include <hip/hip_runtime.h>

// StandardTrafficCoordinator: B=1024, N=64, F=512, H=512.
// pre = states@(63*W1)^T + Am@(states@W2f^T) + msg_d@W2d^T   (associativity)
// R10: spill-free 2 blocks/CU. Empirical law on this toolchain: VGPR cap =
// 256/launch_bounds_arg (split VGPR/AGPR accounting, R3/R6/R7 data). So shrink
// total regs instead of capping: h processed in 2 chunks of 32 rows/wave ->
// acc[2][4]=32 AGPR; projections (pp/vv) accumulate across chunks. S re-staged
// per (chunk,half) (2nd pass L3-resident). (512,3): cap 85 >= demand ~75.

typedef __attribute__((ext_vector_type(8))) short bf16x8;
typedef __attribute__((ext_vector_type(4))) float f32x4;
typedef __attribute__((ext_vector_type(4))) unsigned short us4;

__device__ __forceinline__ unsigned short f2bf(float x) {
  union { float f; unsigned int u; } c; c.f = x;
  return (unsigned short)((c.u + 0x7FFFu + ((c.u >> 16) & 1u)) >> 16);  // RNE
}

// prep: Wgb[h][k] = bf16((k<512?63:1)*Wg[h][k]); coalesced, 2 floats/thread.
// auxw[h][8] = {63*bg, W2d0, W2d1, W4[0], W4[1], W5, 0, 0}
__global__ __launch_bounds__(256) void prep_kernel(
    const float* __restrict__ Wg, const float* __restrict__ bg,
    const float* __restrict__ W4, const float* __restrict__ W5,
    unsigned short* __restrict__ Wgb, float* __restrict__ auxw)
{
  const int id = blockIdx.x * 256 + threadIdx.x;   // 512*512 threads
  const int h = id >> 9;
  const int kp = id & 511;
  const int k = kp * 2;
  const float* row = Wg + h * 1026;
  const float s = (k < 512) ? 63.0f : 1.0f;
  unsigned int lo = f2bf(s * row[k]);
  unsigned int hi = f2bf(s * row[k + 1]);
  *(unsigned int*)&Wgb[h * 1024 + k] = lo | (hi << 16);
  if (kp == 0) {
    float* a = auxw + h * 8;
    a[0] = 63.0f * bg[h];
    a[1] = row[1024];
    a[2] = row[1025];
    a[3] = W4[h];
    a[4] = W4[512 + h];
    a[5] = W5[h];
    a[6] = 0.0f; a[7] = 0.0f;
  }
}

__global__ __launch_bounds__(512, 3) void traffic_kernel(
    const float* __restrict__ locs, const float* __restrict__ states,
    const unsigned short* __restrict__ Wgb, const float* __restrict__ auxw,
    const float* __restrict__ b4, const float* __restrict__ b5,
    float* __restrict__ out)
{
  __shared__ unsigned short S[32 * 520];     // 32 state rows, bf16, +8 pad (33.3 KB)
  __shared__ unsigned short Am[64 * 72];     // adjacency, diag 0 (9.2 KB)
  __shared__ unsigned short scr[8][16 * 40]; // per-wave transpose scratch (10.2 KB)
  __shared__ float locs_s[128];
  __shared__ float msgd[128];
  __shared__ float red[8 * 64 * 3];          // 6 KB
  // total ~59.9 KB -> 2 blocks/CU (LDS). Regs: ~75 VGPR + ~40 AGPR <= 128 total.

  const int t = threadIdx.x;
  const int b = blockIdx.x;
  const int lane = t & 63;
  const int w = t >> 6;                      // 8 waves
  const int llo = lane & 15;
  const int lhi = lane >> 4;
  const int hw = w * 64;                     // wave's 64-row h-slice

  if (t < 128) locs_s[t] = locs[b * 128 + t];
  __syncthreads();

  // ---- Phase A: adjacency Am + msg_d (thread = (row i, 8-col strip)) ----
  {
    const int i = t >> 3;                    // 0..63
    const int j0 = (t & 7) * 8;              // 0..56
    const float xi = locs_s[2*i], yi = locs_s[2*i+1];
    float a[8]; float psum = 0.f;
#pragma unroll
    for (int q = 0; q < 8; ++q) {
      int j = j0 + q;
      float dx = xi - locs_s[2*j];
      float dy = yi - locs_s[2*j+1];
      a[q] = (dx*dx + dy*dy < 1.0f) ? 1.0f : 0.0f;
      psum += a[q];
    }
    psum += __shfl_xor(psum, 1);
    psum += __shfl_xor(psum, 2);
    psum += __shfl_xor(psum, 4);             // row degree incl. self
    const float inv = 1.0f / psum;
    float m0 = 0.f, m1 = 0.f;
#pragma unroll
    for (int q = 0; q < 8; ++q) {
      int j = j0 + q;
      float v = (j == i) ? 0.f : a[q] * inv; // zero diagonal AFTER normalize
      a[q] = v;
      m0 += v * (xi - locs_s[2*j]);
      m1 += v * (yi - locs_s[2*j+1]);
    }
    m0 += __shfl_xor(m0, 1); m0 += __shfl_xor(m0, 2); m0 += __shfl_xor(m0, 4);
    m1 += __shfl_xor(m1, 1); m1 += __shfl_xor(m1, 2); m1 += __shfl_xor(m1, 4);
    if ((t & 7) == 0) { msgd[2*i] = m0; msgd[2*i+1] = m1; }
    union { unsigned short h8[8]; uint4 v4; } pk;
#pragma unroll
    for (int q = 0; q < 8; ++q) pk.h8[q] = f2bf(a[q]);
    *(uint4*)&Am[i*72 + j0] = pk.v4;         // 144=16*9 -> 16B aligned
  }

  // ---- staging: 32 state rows (one half) f32 -> S bf16 ----
  auto stageS = [&](int half) {
    const float4* sb = (const float4*)(states + (size_t)b * 32768 + half * 16384);
#pragma unroll
    for (int it = 0; it < 8; ++it) {
      int id = it * 512 + t;
      int j = id >> 7;
      int f0 = (id & 127) * 4;
      float4 v = sb[id];
      us4 s4;
      s4.x = f2bf(v.x); s4.y = f2bf(v.y);
      s4.z = f2bf(v.z); s4.w = f2bf(v.w);
      *(us4*)&S[j * 520 + f0] = s4;
    }
  };

  f32x4 acc[2][4];        // pre^T chunk accumulator [mt][nt] = 32 regs (AGPR)
  bf16x8 afr_reg[2];      // U2 A-fragments for D' (8 regs)
  unsigned short* sc = &scr[w][0];
  const size_t wb = (size_t)(hw + llo) * 1024 + lhi * 8;  // Wgb lane base

  // C1 chunk (1 mt): au = W2f(16 rows c) x S-half; transpose -> afr_reg[slot]
  auto c1_chunk = [&](int c, int slot) {
    f32x4 au[2];
    au[0] = f32x4{0.f,0.f,0.f,0.f};
    au[1] = f32x4{0.f,0.f,0.f,0.f};
#pragma unroll 4
    for (int ks = 0; ks < 16; ++ks) {
      bf16x8 afr = *(const bf16x8*)&Wgb[wb + (size_t)c*16384 + 512 + ks*32];
      bf16x8 bfr0 = *(const bf16x8*)&S[(llo)*520 + ks*32 + lhi*8];
      bf16x8 bfr1 = *(const bf16x8*)&S[(16 + llo)*520 + ks*32 + lhi*8];
      au[0] = __builtin_amdgcn_mfma_f32_16x16x32_bf16(afr, bfr0, au[0], 0, 0, 0);
      au[1] = __builtin_amdgcn_mfma_f32_16x16x32_bf16(afr, bfr1, au[1], 0, 0, 0);
    }
    // transpose: C-layout (row=lhi*4+r, col=llo) -> A-frag (row=llo, k=lhi*8..)
#pragma unroll
    for (int n = 0; n < 2; ++n)
#pragma unroll
      for (int r = 0; r < 4; ++r)
        sc[(lhi*4 + r)*40 + n*16 + llo] = f2bf(au[n][r]);
    // same-wave in-order DS pipe: reads see prior writes (validated pattern)
    afr_reg[slot] = *(const bf16x8*)&sc[llo*40 + lhi*8];
  };

  // D': acc += U2(regs) x Am(cols half*32..+31), K=32
  auto dprime = [&](int half) {
#pragma unroll
    for (int nt = 0; nt < 4; ++nt) {
      bf16x8 bfr = *(const bf16x8*)&Am[(nt*16 + llo)*72 + half*32 + lhi*8];
#pragma unroll
      for (int mt = 0; mt < 2; ++mt)
        acc[mt][nt] = __builtin_amdgcn_mfma_f32_16x16x32_bf16(afr_reg[mt], bfr, acc[mt][nt], 0, 0, 0);
    }
  };

  // C2: acc[mt][half*2+n] += 63W1(rows ch*2+mt) x S-half
  auto c2_half = [&](int ch, int half) {
#pragma unroll 2
    for (int ks = 0; ks < 16; ++ks) {
      bf16x8 afr[2], bfr[2];
#pragma unroll
      for (int mt = 0; mt < 2; ++mt)
        afr[mt] = *(const bf16x8*)&Wgb[wb + (size_t)(ch*2+mt)*16384 + ks*32];
#pragma unroll
      for (int n = 0; n < 2; ++n)
        bfr[n] = *(const bf16x8*)&S[(n*16 + llo)*520 + ks*32 + lhi*8];
#pragma unroll
      for (int mt = 0; mt < 2; ++mt)
#pragma unroll
        for (int n = 0; n < 2; ++n)
          acc[mt][half*2 + n] = __builtin_amdgcn_mfma_f32_16x16x32_bf16(afr[mt], bfr[n], acc[mt][half*2 + n], 0, 0, 0);
    }
  };

  // persistent projection accumulators (summed over ALL h via chunk loop)
  float mdx[4], mdy[4];
#pragma unroll
  for (int nt = 0; nt < 4; ++nt) {
    mdx[nt] = msgd[2*(nt*16 + llo)];         // msgd valid after Phase A barrier below
    mdy[nt] = msgd[2*(nt*16 + llo) + 1];
  }
  float pp0[4] = {0,0,0,0}, pp1[4] = {0,0,0,0}, vv[4] = {0,0,0,0};

  for (int ch = 0; ch < 2; ++ch) {
#pragma unroll
    for (int half = 0; half < 2; ++half) {
      __syncthreads();               // Phase A done (1st iter) / prev S reads done
      stageS(half);
      __syncthreads();
      c1_chunk(ch*2 + 0, 0);
      c1_chunk(ch*2 + 1, 1);
      if (half == 0) {
#pragma unroll
        for (int mt = 0; mt < 2; ++mt)
#pragma unroll
          for (int nt = 0; nt < 4; ++nt) acc[mt][nt] = f32x4{0.f,0.f,0.f,0.f};
      }
      dprime(half);
      c2_half(ch, half);
    }
    // per-chunk epilogue: + msg_d@W2d + 63bg, relu, accumulate projections
#pragma unroll
    for (int mt = 0; mt < 2; ++mt) {
#pragma unroll
      for (int r = 0; r < 4; ++r) {
        int hh = hw + ch*32 + mt*16 + lhi*4 + r;
        float4 ax0 = *(const float4*)&auxw[hh*8];      // {63bg, W2d0, W2d1, W4_0}
        float4 ax1 = *(const float4*)&auxw[hh*8 + 4];  // {W4_1, W5, 0, 0}
#pragma unroll
        for (int nt = 0; nt < 4; ++nt) {
          float val = acc[mt][nt][r] + ax0.x + mdx[nt]*ax0.y + mdy[nt]*ax0.z;
          val = fmaxf(val, 0.f);
          pp0[nt] += val * ax0.w;
          pp1[nt] += val * ax1.x;
          vv[nt]  += val * ax1.y;
        }
      }
    }
  }

  // ---- final reduce: over lhi groups (shfl), then over waves (LDS) ----
#pragma unroll
  for (int nt = 0; nt < 4; ++nt) {
    pp0[nt] += __shfl_xor(pp0[nt], 16); pp0[nt] += __shfl_xor(pp0[nt], 32);
    pp1[nt] += __shfl_xor(pp1[nt], 16); pp1[nt] += __shfl_xor(pp1[nt], 32);
    vv[nt]  += __shfl_xor(vv[nt], 16);  vv[nt]  += __shfl_xor(vv[nt], 32);
  }
  if (lane < 16) {
#pragma unroll
    for (int nt = 0; nt < 4; ++nt) {
      int i = nt*16 + llo;
      red[(w*64 + i)*3 + 0] = pp0[nt];
      red[(w*64 + i)*3 + 1] = pp1[nt];
      red[(w*64 + i)*3 + 2] = vv[nt];
    }
  }
  __syncthreads();
  if (t < 192) {                     // cross-wave reduce + bias + store
    int o = t >> 6;                  // 0,1 -> policies; 2 -> values
    int i = t & 63;
    float s = 0.f;
#pragma unroll
    for (int ww = 0; ww < 8; ++ww) s += red[(ww*64 + i)*3 + o];
    s += (o < 2) ? b4[o] : b5[0];
    if (o < 2) out[((size_t)b*64 + i)*2 + o] = s;
    else       out[(size_t)131072 + (size_t)b*64 + i] = s;
  }
}

extern "C" void kernel_launch(void* const* d_in, const int* in_sizes, int n_in,
                              void* d_out, int out_size, void* d_ws, size_t ws_size,
                              hipStream_t stream)
{
  const float* locs   = (const float*)d_in[0];
  const float* states = (const float*)d_in[1];
  const float* Wg     = (const float*)d_in[2];
  const float* bg     = (const float*)d_in[3];
  const float* W4     = (const float*)d_in[4];
  const float* b4     = (const float*)d_in[5];
  const float* W5     = (const float*)d_in[6];
  const float* b5     = (const float*)d_in[7];

  unsigned short* Wgb = (unsigned short*)d_ws;                   // 1 MB bf16 weights
  float* auxw = (float*)((char*)d_ws + 512 * 1024 * 2);          // 16 KB epilogue table

  prep_kernel<<<1024, 256, 0, stream>>>(Wg, bg, W4, W5, Wgb, auxw);
  traffic_kernel<<<1024, 512, 0, stream>>>(locs, states, Wgb, auxw, b4, b5, (float*)d_out);
}

// Round 13
// 328.063 us; speedup vs baseline: 1.3639x; 1.3639x over previous
//
#include <hip/hip_runtime.h>

// StandardTrafficCoordinator: B=1024, N=64, F=512, H=512.
// R12: batched-GEMM restructure. pre^T = [63W1; W2f] x states_all^T as ONE
// 1024x65536x512 GEMM (m97 pattern: global_load_lds w16, XOR-swizzled, dbuf,
// 1 barrier/step). Block = (mtile of 64 h) x (itile of 128 i = 2 batches);
// D' (Am x U2^T) + relu + W4/W5 projections fused in-block; atomicAdd out.
// Prereq kernels: states->bf16 (read f32 once), adjacency->Amb/msgd, Wgb/auxw.
// Needs 76MB ws; falls back to proven R11 kernel if ws_size too small.

typedef __attribute__((ext_vector_type(8))) short bf16x8;
typedef __attribute__((ext_vector_type(4))) float f32x4;
typedef __attribute__((ext_vector_type(4))) unsigned short us4;

__device__ __forceinline__ unsigned short f2bf(float x) {
  union { float f; unsigned int u; } c; c.f = x;
  return (unsigned short)((c.u + 0x7FFFu + ((c.u >> 16) & 1u)) >> 16);  // RNE
}

__device__ __forceinline__ void gld16(const void* g, void* l) {
  __builtin_amdgcn_global_load_lds(
      (const __attribute__((address_space(1))) void*)g,
      (__attribute__((address_space(3))) void*)l, 16, 0, 0);
}

#define MFMA __builtin_amdgcn_mfma_f32_16x16x32_bf16

// ---- prep: Wgb[h][k] = bf16((k<512?63:1)*Wg[h][k]); auxw[h][8] table ----
__global__ __launch_bounds__(256) void prep_kernel(
    const float* __restrict__ Wg, const float* __restrict__ bg,
    const float* __restrict__ W4, const float* __restrict__ W5,
    unsigned short* __restrict__ Wgb, float* __restrict__ auxw)
{
  const int id = blockIdx.x * 256 + threadIdx.x;
  const int h = id >> 9;
  const int kp = id & 511;
  const int k = kp * 2;
  const float* row = Wg + h * 1026;
  const float s = (k < 512) ? 63.0f : 1.0f;
  unsigned int lo = f2bf(s * row[k]);
  unsigned int hi = f2bf(s * row[k + 1]);
  *(unsigned int*)&Wgb[h * 1024 + k] = lo | (hi << 16);
  if (kp == 0) {
    float* a = auxw + h * 8;
    a[0] = 63.0f * bg[h];
    a[1] = row[1024];
    a[2] = row[1025];
    a[3] = W4[h];
    a[4] = W4[512 + h];
    a[5] = W5[h];
    a[6] = 0.0f; a[7] = 0.0f;
  }
}

// ---- conv: states f32 -> bf16 [1024*64][512], 8 elems/thread ----
__global__ __launch_bounds__(256) void conv_kernel(
    const float* __restrict__ s, unsigned short* __restrict__ sb)
{
  size_t id = (size_t)blockIdx.x * 256 + threadIdx.x;
  const float4* p = (const float4*)(s + id * 8);
  float4 v0 = p[0], v1 = p[1];
  union { unsigned short h[8]; uint4 u; } pk;
  pk.h[0]=f2bf(v0.x); pk.h[1]=f2bf(v0.y); pk.h[2]=f2bf(v0.z); pk.h[3]=f2bf(v0.w);
  pk.h[4]=f2bf(v1.x); pk.h[5]=f2bf(v1.y); pk.h[6]=f2bf(v1.z); pk.h[7]=f2bf(v1.w);
  *(uint4*)&sb[id * 8] = pk.u;
}

// ---- adj: Am (row-norm, diag0) -> Amb[b][64][72] bf16; msgd[b][64][2] f32 ----
__global__ __launch_bounds__(512) void adj_kernel(
    const float* __restrict__ locs, unsigned short* __restrict__ Amb,
    float* __restrict__ msgd)
{
  __shared__ float locs_s[128];
  const int t = threadIdx.x, b = blockIdx.x;
  if (t < 128) locs_s[t] = locs[b * 128 + t];
  __syncthreads();
  const int i = t >> 3;
  const int j0 = (t & 7) * 8;
  const float xi = locs_s[2*i], yi = locs_s[2*i+1];
  float a[8]; float psum = 0.f;
#pragma unroll
  for (int q = 0; q < 8; ++q) {
    int j = j0 + q;
    float dx = xi - locs_s[2*j];
    float dy = yi - locs_s[2*j+1];
    a[q] = (dx*dx + dy*dy < 1.0f) ? 1.0f : 0.0f;
    psum += a[q];
  }
  psum += __shfl_xor(psum, 1);
  psum += __shfl_xor(psum, 2);
  psum += __shfl_xor(psum, 4);
  const float inv = 1.0f / psum;
  float m0 = 0.f, m1 = 0.f;
#pragma unroll
  for (int q = 0; q < 8; ++q) {
    int j = j0 + q;
    float v = (j == i) ? 0.f : a[q] * inv;
    a[q] = v;
    m0 += v * (xi - locs_s[2*j]);
    m1 += v * (yi - locs_s[2*j+1]);
  }
  m0 += __shfl_xor(m0, 1); m0 += __shfl_xor(m0, 2); m0 += __shfl_xor(m0, 4);
  m1 += __shfl_xor(m1, 1); m1 += __shfl_xor(m1, 2); m1 += __shfl_xor(m1, 4);
  if ((t & 7) == 0) { msgd[b*128 + 2*i] = m0; msgd[b*128 + 2*i + 1] = m1; }
  union { unsigned short h8[8]; uint4 v4; } pk;
#pragma unroll
  for (int q = 0; q < 8; ++q) pk.h8[q] = f2bf(a[q]);
  *(uint4*)&Amb[(size_t)b * 4608 + i * 72 + j0] = pk.v4;
}

// ---- main: 64h x 128i tile, K=512, gload_lds dbuf, fused D'+epilogue ----
__global__ __launch_bounds__(256, 2) void gemm_kernel(
    const unsigned short* __restrict__ Wgb, const unsigned short* __restrict__ statesb,
    const unsigned short* __restrict__ Amb, const float* __restrict__ msgd,
    const float* __restrict__ auxw, const float* __restrict__ b4,
    const float* __restrict__ b5, float* __restrict__ out)
{
  __shared__ unsigned short Abuf[2][2][4096];  // [buf][mat][64*64] (32 KB)
  __shared__ unsigned short Bbuf[2][8192];     // [buf][128*64]     (32 KB)

  const int t = threadIdx.x;
  const int lane = t & 63;
  const int w = t >> 6;                        // 4 waves
  const int llo = lane & 15;
  const int lhi = lane >> 4;
  const int bid = blockIdx.x;
  const int mtile = bid & 7;                   // h-tile (64 rows)
  const int itile = bid >> 3;                  // col-tile (128 i = 2 batches)
  const int lrow = lane >> 3;                  // staging: row within 8-row group
  const int lchunk = (lane & 7) ^ lrow;        // inverse-swizzled source chunk

  // stage one BK=64 K-slab of A (both mats) + B into buf (wave-split instrs)
  auto stage = [&](int buf, int ko) {
#pragma unroll
    for (int s = 0; s < 4; ++s) {              // B: 128 rows = 16 instrs, 4/wave
      int q = w * 4 + s;
      const char* g = (const char*)statesb +
          ((size_t)(itile * 128 + q * 8 + lrow) * 512 + ko) * 2 + lchunk * 16;
      gld16(g, (void*)&Bbuf[buf][q * 512]);
    }
#pragma unroll
    for (int mat = 0; mat < 2; ++mat)          // A: 2 mats x 8 instrs, 4/wave
#pragma unroll
      for (int s = 0; s < 2; ++s) {
        int q = w * 2 + s;
        const char* g = (const char*)Wgb +
            ((size_t)(mtile * 64 + q * 8 + lrow) * 1024 + mat * 512 + ko) * 2 + lchunk * 16;
        gld16(g, (void*)&Abuf[buf][mat][q * 512]);
      }
  };

  f32x4 a1[4][2], a2[4][2];                    // pre-partial (W1'), U2 (W2f)
#pragma unroll
  for (int m = 0; m < 4; ++m)
#pragma unroll
    for (int n = 0; n < 2; ++n) {
      a1[m][n] = f32x4{0.f,0.f,0.f,0.f};
      a2[m][n] = f32x4{0.f,0.f,0.f,0.f};
    }

  int buf = 0;
  stage(0, 0);
  __syncthreads();                             // drain prologue stage

  for (int ks = 0; ks < 8; ++ks) {             // K=512, BK=64
    if (ks < 7) stage(buf ^ 1, (ks + 1) * 64); // prefetch next slab
#pragma unroll
    for (int kk = 0; kk < 2; ++kk) {           // 2 x K=32 substeps
      bf16x8 af1[4], af2[4], bf[2];
#pragma unroll
      for (int m = 0; m < 4; ++m) {
        int hl = m * 16 + llo;
        int slot = (kk * 4 + lhi) ^ (hl & 7);  // swizzled read
        af1[m] = *(const bf16x8*)&Abuf[buf][0][hl * 64 + slot * 8];
        af2[m] = *(const bf16x8*)&Abuf[buf][1][hl * 64 + slot * 8];
      }
#pragma unroll
      for (int n = 0; n < 2; ++n) {
        int iw = w * 32 + n * 16 + llo;
        int slot = (kk * 4 + lhi) ^ (iw & 7);
        bf[n] = *(const bf16x8*)&Bbuf[buf][iw * 64 + slot * 8];
      }
#pragma unroll
      for (int m = 0; m < 4; ++m)
#pragma unroll
        for (int n = 0; n < 2; ++n) {
          a1[m][n] = MFMA(af1[m], bf[n], a1[m][n], 0, 0, 0);
          a2[m][n] = MFMA(af2[m], bf[n], a2[m][n], 0, 0, 0);
        }
    }
    __syncthreads();                           // drain prefetch + release buf
    buf ^= 1;
  }

  // ---- U2 -> LDS transpose (reuse Bbuf; all reads done at last barrier) ----
  unsigned short* u2t = &Bbuf[0][0];           // [2 batches][64 h][72] bf16
  const int bi = w >> 1;                       // wave's batch within itile
  const int jhalf = (w & 1) * 32;              // wave's j-range
#pragma unroll
  for (int m = 0; m < 4; ++m)
#pragma unroll
    for (int n = 0; n < 2; ++n)
#pragma unroll
      for (int r = 0; r < 4; ++r)
        u2t[bi * 4608 + (m * 16 + lhi * 4 + r) * 72 + jhalf + n * 16 + llo] =
            f2bf(a2[m][n][r]);
  __syncthreads();

  // ---- D': a1 += U2(A-frags from u2t) x Am(B rows from global, L2-hot) ----
#pragma unroll
  for (int ks = 0; ks < 2; ++ks) {
    bf16x8 af[4], bfm[2];
#pragma unroll
    for (int m = 0; m < 4; ++m)
      af[m] = *(const bf16x8*)&u2t[bi * 4608 + (m * 16 + llo) * 72 + ks * 32 + lhi * 8];
#pragma unroll
    for (int n = 0; n < 2; ++n) {
      int il = jhalf + n * 16 + llo;
      bfm[n] = *(const bf16x8*)&Amb[(size_t)(itile * 2 + bi) * 4608 + il * 72 + ks * 32 + lhi * 8];
    }
#pragma unroll
    for (int m = 0; m < 4; ++m)
#pragma unroll
      for (int n = 0; n < 2; ++n)
        a1[m][n] = MFMA(af[m], bfm[n], a1[m][n], 0, 0, 0);
  }

  // ---- epilogue: + msg_d@W2d + 63bg, relu, project, atomic-accumulate ----
  float mdx[2], mdy[2], pp0[2] = {0,0}, pp1[2] = {0,0}, vvv[2] = {0,0};
  const size_t bglob = (size_t)itile * 2 + bi;
#pragma unroll
  for (int n = 0; n < 2; ++n) {
    int il = jhalf + n * 16 + llo;
    mdx[n] = msgd[bglob * 128 + il * 2];
    mdy[n] = msgd[bglob * 128 + il * 2 + 1];
  }
#pragma unroll
  for (int m = 0; m < 4; ++m)
#pragma unroll
    for (int r = 0; r < 4; ++r) {
      int hh = mtile * 64 + m * 16 + lhi * 4 + r;
      float4 ax0 = *(const float4*)&auxw[hh * 8];     // {63bg, W2d0, W2d1, W4_0}
      float4 ax1 = *(const float4*)&auxw[hh * 8 + 4]; // {W4_1, W5, 0, 0}
#pragma unroll
      for (int n = 0; n < 2; ++n) {
        float val = a1[m][n][r] + ax0.x + mdx[n] * ax0.y + mdy[n] * ax0.z;
        val = fmaxf(val, 0.f);
        pp0[n] += val * ax0.w;
        pp1[n] += val * ax1.x;
        vvv[n] += val * ax1.y;
      }
    }
#pragma unroll
  for (int n = 0; n < 2; ++n) {                // sum over lhi groups (h)
    pp0[n] += __shfl_xor(pp0[n], 16); pp0[n] += __shfl_xor(pp0[n], 32);
    pp1[n] += __shfl_xor(pp1[n], 16); pp1[n] += __shfl_xor(pp1[n], 32);
    vvv[n] += __shfl_xor(vvv[n], 16); vvv[n] += __shfl_xor(vvv[n], 32);
  }
  if (lane < 16) {
    float bb0 = (mtile == 0) ? b4[0] : 0.f;    // bias added exactly once
    float bb1 = (mtile == 0) ? b4[1] : 0.f;
    float bb2 = (mtile == 0) ? b5[0] : 0.f;
#pragma unroll
    for (int n = 0; n < 2; ++n) {
      size_t ig = (size_t)itile * 128 + w * 32 + n * 16 + llo;  // = b*64+i
      atomicAdd(&out[ig * 2],     pp0[n] + bb0);
      atomicAdd(&out[ig * 2 + 1], pp1[n] + bb1);
      atomicAdd(&out[131072 + ig], vvv[n] + bb2);
    }
  }
}

// ==================== R11 fallback (proven) if ws too small ====================
__global__ __launch_bounds__(512, 3) void traffic_fb(
    const float* __restrict__ locs, const float* __restrict__ states,
    const unsigned short* __restrict__ Wgb, const float* __restrict__ auxw,
    const float* __restrict__ b4, const float* __restrict__ b5,
    float* __restrict__ out)
{
  __shared__ unsigned short S[32 * 520];
  __shared__ unsigned short Am[64 * 72];
  __shared__ unsigned short scr[8][16 * 40];
  __shared__ float locs_s[128];
  __shared__ float msgd[128];
  __shared__ float red[8 * 64 * 3];

  const int t = threadIdx.x;
  const int b = blockIdx.x;
  const int lane = t & 63;
  const int w = t >> 6;
  const int llo = lane & 15;
  const int lhi = lane >> 4;
  const int hw = w * 64;

  if (t < 128) locs_s[t] = locs[b * 128 + t];
  __syncthreads();
  {
    const int i = t >> 3;
    const int j0 = (t & 7) * 8;
    const float xi = locs_s[2*i], yi = locs_s[2*i+1];
    float a[8]; float psum = 0.f;
#pragma unroll
    for (int q = 0; q < 8; ++q) {
      int j = j0 + q;
      float dx = xi - locs_s[2*j];
      float dy = yi - locs_s[2*j+1];
      a[q] = (dx*dx + dy*dy < 1.0f) ? 1.0f : 0.0f;
      psum += a[q];
    }
    psum += __shfl_xor(psum, 1);
    psum += __shfl_xor(psum, 2);
    psum += __shfl_xor(psum, 4);
    const float inv = 1.0f / psum;
    float m0 = 0.f, m1 = 0.f;
#pragma unroll
    for (int q = 0; q < 8; ++q) {
      int j = j0 + q;
      float v = (j == i) ? 0.f : a[q] * inv;
      a[q] = v;
      m0 += v * (xi - locs_s[2*j]);
      m1 += v * (yi - locs_s[2*j+1]);
    }
    m0 += __shfl_xor(m0, 1); m0 += __shfl_xor(m0, 2); m0 += __shfl_xor(m0, 4);
    m1 += __shfl_xor(m1, 1); m1 += __shfl_xor(m1, 2); m1 += __shfl_xor(m1, 4);
    if ((t & 7) == 0) { msgd[2*i] = m0; msgd[2*i+1] = m1; }
    union { unsigned short h8[8]; uint4 v4; } pk;
#pragma unroll
    for (int q = 0; q < 8; ++q) pk.h8[q] = f2bf(a[q]);
    *(uint4*)&Am[i*72 + j0] = pk.v4;
  }
  auto stageS = [&](int half) {
    const float4* sb = (const float4*)(states + (size_t)b * 32768 + half * 16384);
#pragma unroll
    for (int it = 0; it < 8; ++it) {
      int id = it * 512 + t;
      int j = id >> 7;
      int f0 = (id & 127) * 4;
      float4 v = sb[id];
      us4 s4;
      s4.x = f2bf(v.x); s4.y = f2bf(v.y);
      s4.z = f2bf(v.z); s4.w = f2bf(v.w);
      *(us4*)&S[j * 520 + f0] = s4;
    }
  };
  f32x4 acc[2][4];
  bf16x8 afr_reg[2];
  unsigned short* sc = &scr[w][0];
  const size_t wb = (size_t)(hw + llo) * 1024 + lhi * 8;
  auto c1_chunk = [&](int c, int slot) {
    f32x4 au[2];
    au[0] = f32x4{0.f,0.f,0.f,0.f};
    au[1] = f32x4{0.f,0.f,0.f,0.f};
#pragma unroll 4
    for (int ks = 0; ks < 16; ++ks) {
      bf16x8 afr = *(const bf16x8*)&Wgb[wb + (size_t)c*16384 + 512 + ks*32];
      bf16x8 bfr0 = *(const bf16x8*)&S[(llo)*520 + ks*32 + lhi*8];
      bf16x8 bfr1 = *(const bf16x8*)&S[(16 + llo)*520 + ks*32 + lhi*8];
      au[0] = MFMA(afr, bfr0, au[0], 0, 0, 0);
      au[1] = MFMA(afr, bfr1, au[1], 0, 0, 0);
    }
#pragma unroll
    for (int n = 0; n < 2; ++n)
#pragma unroll
      for (int r = 0; r < 4; ++r)
        sc[(lhi*4 + r)*40 + n*16 + llo] = f2bf(au[n][r]);
    afr_reg[slot] = *(const bf16x8*)&sc[llo*40 + lhi*8];
  };
  auto dprime = [&](int half) {
#pragma unroll
    for (int nt = 0; nt < 4; ++nt) {
      bf16x8 bfr = *(const bf16x8*)&Am[(nt*16 + llo)*72 + half*32 + lhi*8];
#pragma unroll
      for (int mt = 0; mt < 2; ++mt)
        acc[mt][nt] = MFMA(afr_reg[mt], bfr, acc[mt][nt], 0, 0, 0);
    }
  };
  auto c2_half = [&](int ch, int half) {
#pragma unroll 2
    for (int ks = 0; ks < 16; ++ks) {
      bf16x8 afr[2], bfr[2];
#pragma unroll
      for (int mt = 0; mt < 2; ++mt)
        afr[mt] = *(const bf16x8*)&Wgb[wb + (size_t)(ch*2+mt)*16384 + ks*32];
#pragma unroll
      for (int n = 0; n < 2; ++n)
        bfr[n] = *(const bf16x8*)&S[(n*16 + llo)*520 + ks*32 + lhi*8];
#pragma unroll
      for (int mt = 0; mt < 2; ++mt)
#pragma unroll
        for (int n = 0; n < 2; ++n)
          acc[mt][half*2 + n] = MFMA(afr[mt], bfr[n], acc[mt][half*2 + n], 0, 0, 0);
    }
  };
  float mdx[4], mdy[4];
#pragma unroll
  for (int nt = 0; nt < 4; ++nt) {
    mdx[nt] = msgd[2*(nt*16 + llo)];
    mdy[nt] = msgd[2*(nt*16 + llo) + 1];
  }
  float pp0[4] = {0,0,0,0}, pp1[4] = {0,0,0,0}, vv[4] = {0,0,0,0};
  for (int ch = 0; ch < 2; ++ch) {
#pragma unroll
    for (int half = 0; half < 2; ++half) {
      __syncthreads();
      stageS(half);
      __syncthreads();
      c1_chunk(ch*2 + 0, 0);
      c1_chunk(ch*2 + 1, 1);
      if (half == 0) {
#pragma unroll
        for (int mt = 0; mt < 2; ++mt)
#pragma unroll
          for (int nt = 0; nt < 4; ++nt) acc[mt][nt] = f32x4{0.f,0.f,0.f,0.f};
      }
      dprime(half);
      c2_half(ch, half);
    }
#pragma unroll
    for (int mt = 0; mt < 2; ++mt) {
#pragma unroll
      for (int r = 0; r < 4; ++r) {
        int hh = hw + ch*32 + mt*16 + lhi*4 + r;
        float4 ax0 = *(const float4*)&auxw[hh*8];
        float4 ax1 = *(const float4*)&auxw[hh*8 + 4];
#pragma unroll
        for (int nt = 0; nt < 4; ++nt) {
          float val = acc[mt][nt][r] + ax0.x + mdx[nt]*ax0.y + mdy[nt]*ax0.z;
          val = fmaxf(val, 0.f);
          pp0[nt] += val * ax0.w;
          pp1[nt] += val * ax1.x;
          vv[nt]  += val * ax1.y;
        }
      }
    }
  }
#pragma unroll
  for (int nt = 0; nt < 4; ++nt) {
    pp0[nt] += __shfl_xor(pp0[nt], 16); pp0[nt] += __shfl_xor(pp0[nt], 32);
    pp1[nt] += __shfl_xor(pp1[nt], 16); pp1[nt] += __shfl_xor(pp1[nt], 32);
    vv[nt]  += __shfl_xor(vv[nt], 16);  vv[nt]  += __shfl_xor(vv[nt], 32);
  }
  if (lane < 16) {
#pragma unroll
    for (int nt = 0; nt < 4; ++nt) {
      int i = nt*16 + llo;
      red[(w*64 + i)*3 + 0] = pp0[nt];
      red[(w*64 + i)*3 + 1] = pp1[nt];
      red[(w*64 + i)*3 + 2] = vv[nt];
    }
  }
  __syncthreads();
  if (t < 192) {
    int o = t >> 6;
    int i = t & 63;
    float s = 0.f;
#pragma unroll
    for (int ww = 0; ww < 8; ++ww) s += red[(ww*64 + i)*3 + o];
    s += (o < 2) ? b4[o] : b5[0];
    if (o < 2) out[((size_t)b*64 + i)*2 + o] = s;
    else       out[(size_t)131072 + (size_t)b*64 + i] = s;
  }
}

extern "C" void kernel_launch(void* const* d_in, const int* in_sizes, int n_in,
                              void* d_out, int out_size, void* d_ws, size_t ws_size,
                              hipStream_t stream)
{
  const float* locs   = (const float*)d_in[0];
  const float* states = (const float*)d_in[1];
  const float* Wg     = (const float*)d_in[2];
  const float* bg     = (const float*)d_in[3];
  const float* W4     = (const float*)d_in[4];
  const float* b4     = (const float*)d_in[5];
  const float* W5     = (const float*)d_in[6];
  const float* b5     = (const float*)d_in[7];

  char* ws = (char*)d_ws;
  unsigned short* Wgb = (unsigned short*)ws;                       // [0, 1MB)
  float* auxw = (float*)(ws + (1 << 20));                          // 16 KB
  float* msgd_g = (float*)(ws + 0x140000);                         // 512 KB
  unsigned short* Amb = (unsigned short*)(ws + (2 << 20));         // 9.44 MB
  unsigned short* statesb = (unsigned short*)(ws + (12 << 20));    // 64 MB
  const size_t NEED = (size_t)76 << 20;

  prep_kernel<<<1024, 256, 0, stream>>>(Wg, bg, W4, W5, Wgb, auxw);

  if (ws_size >= NEED) {
    hipMemsetAsync(d_out, 0, (size_t)out_size * sizeof(float), stream);
    adj_kernel<<<1024, 512, 0, stream>>>(locs, Amb, msgd_g);
    conv_kernel<<<16384, 256, 0, stream>>>(states, statesb);
    gemm_kernel<<<4096, 256, 0, stream>>>(Wgb, statesb, Amb, msgd_g, auxw,
                                          b4, b5, (float*)d_out);
  } else {
    traffic_fb<<<1024, 512, 0, stream>>>(locs, states, Wgb, auxw, b4, b5,
                                         (float*)d_out);
  }
}